// Round 16
// baseline (355.317 us; speedup 1.0000x reference)
//
#include <hip/hip_runtime.h>
#include <hip/hip_cooperative_groups.h>
#include <math.h>

namespace cg = cooperative_groups;

// LiftSplatShoot constants
#define DNUM 41
#define FH 8
#define FW 22
#define CAMC 64
#define NB 8
#define NCAM 6
#define BN 48
#define NXX 200
#define NXY 200
#define KVOX 40000                // NXX*NXY (NXZ=1)
#define CAM_CH (DNUM + CAMC)      // 105
#define HW (FH * FW)              // 176
#define CAM_STRIDE (CAM_CH * HW)  // 18480
#define OUT_PER_B (CAMC * KVOX)   // 2,560,000 floats per batch (scratch & out)
#define SCRATCH_FLOATS ((size_t)NB * KVOX * CAMC)   // 81.92 MB
#define NCPB (NCAM * FW)          // 132 columns per batch
#define NCOL (NB * NCPB)          // 1056 columns total
#define PIXT (NCOL * FH)          // 8448 pixels
#define NPTS (NCOL * FH * DNUM)   // 346,368 points
#define TASKS_PB (NCPB * DNUM)    // 5412 (col,depth) tasks per batch
#define QUADS_PB (TASKS_PB / 4)   // 1353 quad-tasks per batch
#define TPB 625                   // tiles (64 voxels) per batch
#define MWPB 20                   // bitmap words per batch
#define TSZ 64

// Replicates reference safe_inverse_3x3 in float32, same op order, no fma.
__device__ __forceinline__ void inv3x3(const float* __restrict__ m, float* __restrict__ o) {
  #pragma clang fp contract(off)
  float a=m[0], b=m[1], c=m[2];
  float d=m[3], e=m[4], f=m[5];
  float g=m[6], h=m[7], i=m[8];
  float A  =  e*i - f*h;
  float Bc = -(d*i - f*g);
  float Cc =  d*h - e*g;
  float Dc = -(b*i - c*h);
  float E  =  a*i - c*g;
  float F  = -(a*h - b*g);
  float G  =  b*f - c*e;
  float H  = -(a*f - c*d);
  float I  =  a*e - b*d;
  float det = fmaxf((a*A + b*Bc) + c*Cc, 1e-8f);
  o[0]=A/det;  o[1]=Dc/det; o[2]=G/det;
  o[3]=Bc/det; o[4]=E/det;  o[5]=H/det;
  o[6]=Cc/det; o[7]=F/det;  o[8]=I/det;
}

// Fused cooperative kernel: 4 phases with grid-wide barriers.
// 256 threads/block; XCD-pinned work mapping (block g -> batch b = g&7).
__global__ __launch_bounds__(256) void lss_fused(const float* __restrict__ cam_out,
                                                 const float* __restrict__ rots,
                                                 const float* __restrict__ trans,
                                                 const float* __restrict__ intrins,
                                                 const float* __restrict__ post_rots,
                                                 const float* __restrict__ post_trans,
                                                 float* __restrict__ featT,
                                                 int2* __restrict__ recs,
                                                 unsigned* __restrict__ colMask,
                                                 unsigned* __restrict__ aggDirty,
                                                 float* __restrict__ scratch,
                                                 float* __restrict__ out) {
  #pragma clang fp contract(off)
  cg::grid_group grid = cg::this_grid();
  const int g    = blockIdx.x;
  const int b    = g & 7;
  const int gq   = g >> 3;            // block index within batch
  const int BPB  = gridDim.x >> 3;    // blocks per batch
  const int tid  = threadIdx.x;
  const int wv   = tid >> 6;          // wave 0..3
  const int lane = tid & 63;

  __shared__ float sP[9], sM[9], sPT[3], sTR[3];
  __shared__ float sDep[FH][DNUM + 1];
  __shared__ int   sVox[FH][DNUM + 1];
  __shared__ unsigned sMask[MWPB];
  __shared__ union { unsigned red[256]; float tile[TSZ][TSZ + 1]; } u;

  // ---------------- Phase 1: geometry / softmax / records ----------------
  for (int j = gq; j < NCPB; j += BPB) {
    const int bn  = b*NCAM + (j / FW);
    const int w   = j - (j / FW)*FW;
    const int col = b*NCPB + j;

    if (tid == 0) {
      float P[9], IC[9], M[9];
      inv3x3(post_rots + bn*9, P);
      inv3x3(intrins + bn*9, IC);
      const float* R = rots + bn*9;
      #pragma unroll
      for (int r = 0; r < 3; r++)
        #pragma unroll
        for (int k = 0; k < 3; k++)
          M[r*3+k] = (R[r*3+0]*IC[0+k] + R[r*3+1]*IC[3+k]) + R[r*3+2]*IC[6+k];
      #pragma unroll
      for (int q = 0; q < 9; q++) { sP[q] = P[q]; sM[q] = M[q]; }
    } else if (tid >= 8 && tid < 11) {
      sPT[tid-8]  = post_trans[bn*3 + (tid-8)];
    } else if (tid >= 11 && tid < 14) {
      sTR[tid-11] = trans[bn*3 + (tid-11)];
    } else if (tid >= 64 && tid < 64 + MWPB) {
      sMask[tid-64] = 0u;
    }

    const int colbase = bn*CAM_STRIDE + w;

    // featT: 512 values with 256 threads (2 each), write side coalesced
    for (int idx = tid; idx < FH*CAMC; idx += 256) {
      int fh = idx >> 6, c = idx & 63;
      featT[((size_t)(col*FH + fh))*CAMC + c] = cam_out[colbase + (DNUM + c)*HW + fh*FW];
    }
    __syncthreads();

    const float fx = (float)((double)w * (351.0 / 21.0));

    // wave wv handles rows h = wv and wv+4
    #pragma unroll
    for (int r = 0; r < 2; r++) {
      const int h = wv + r*4;
      float logit = (lane < DNUM) ? cam_out[colbase + lane*HW + h*FW] : -INFINITY;
      float mx = logit;
      #pragma unroll
      for (int off = 32; off >= 1; off >>= 1) mx = fmaxf(mx, __shfl_xor(mx, off, 64));
      float e = expf(logit - mx);
      float s = e;
      #pragma unroll
      for (int off = 32; off >= 1; off >>= 1) s += __shfl_xor(s, off, 64);
      if (lane < DNUM) {
        float fy = (float)((double)h * (127.0 / 7.0));
        float fz = 4.0f + (float)lane;
        float p0 = fx - sPT[0], p1 = fy - sPT[1], p2 = fz - sPT[2];
        float q0 = (sP[0]*p0 + sP[1]*p1) + sP[2]*p2;
        float q1 = (sP[3]*p0 + sP[4]*p1) + sP[5]*p2;
        float q2 = (sP[6]*p0 + sP[7]*p1) + sP[8]*p2;
        float r0 = q0*q2, r1 = q1*q2, r2 = q2;
        float g0 = ((sM[0]*r0 + sM[1]*r1) + sM[2]*r2) + sTR[0];
        float g1 = ((sM[3]*r0 + sM[4]*r1) + sM[5]*r2) + sTR[1];
        float g2 = ((sM[6]*r0 + sM[7]*r1) + sM[8]*r2) + sTR[2];
        int ix = (int)((g0 + 50.0f) / 0.5f);
        int iy = (int)((g1 + 50.0f) / 0.5f);
        int iz = (int)((g2 + 10.0f) / 20.0f);
        bool kept = (ix >= 0) & (ix < NXX) & (iy >= 0) & (iy < NXY) & (iz == 0);
        int v = ix*NXY + iy;
        sVox[h][lane] = kept ? v : -1;
        sDep[h][lane] = e / s;
        if (kept) {
          int t = v >> 6;
          atomicOr(&sMask[t >> 5], 1u << (t & 31));
        }
      }
    }
    __syncthreads();

    // records + per-column mask
    int2* __restrict__ rc = recs + (size_t)col*DNUM*FH;
    for (int e = tid; e < DNUM*FH; e += 256) {
      int d = e >> 3, h = e & 7;
      rc[e] = make_int2(sVox[h][d], __float_as_int(sDep[h][d]));
    }
    if (tid < MWPB) colMask[col*MWPB + tid] = sMask[tid];
    __syncthreads();
  }
  __threadfence();
  grid.sync();

  // ---------------- Phase 2: OR-reduce masks, zero dirty tiles ----------------
  for (int t = gq; t < TPB; t += BPB) {
    const int wd = t >> 5, bit = t & 31;
    unsigned m = 0u;
    if (tid < NCPB) m = colMask[(size_t)(b*NCPB + tid)*MWPB + wd];
    u.red[tid] = m;
    __syncthreads();
    #pragma unroll
    for (int off = 128; off >= 1; off >>= 1) {
      if (tid < off) u.red[tid] |= u.red[tid + off];
      __syncthreads();
    }
    const unsigned word = u.red[0];
    if (tid == 0 && bit == 0) aggDirty[b*MWPB + wd] = word;
    if ((word >> bit) & 1u) {
      const float4 z = make_float4(0.f, 0.f, 0.f, 0.f);
      float4* p = ((float4*)scratch) + (size_t)b*(OUT_PER_B/4) + (size_t)t*1024 + tid;
      p[0] = z; p[256] = z; p[512] = z; p[768] = z;
    }
    __syncthreads();
  }
  __threadfence();
  grid.sync();

  // ---------------- Phase 3: merged atomics ----------------
  for (int qt = gq; qt < QUADS_PB; qt += BPB) {
    const int task = qt*4 + wv;         // < 5412 (1353*4 exactly)
    const int j    = task / DNUM;
    const int d    = task - j*DNUM;
    const int col  = b*NCPB + j;

    const int2* __restrict__ r8 = recs + ((size_t)col*DNUM + d)*FH;
    int   vox[FH];
    float dep[FH];
    #pragma unroll
    for (int h = 0; h < FH; h++) {
      int2 e = r8[h];
      vox[h] = e.x;
      dep[h] = __int_as_float(e.y);
    }
    float f[FH];
    const float* __restrict__ ft = featT + (size_t)col*FH*CAMC + lane;
    #pragma unroll
    for (int h = 0; h < FH; h++) f[h] = ft[h*CAMC];

    float* __restrict__ sb = scratch + (size_t)b*OUT_PER_B + lane;
    unsigned done = 0;
    #pragma unroll
    for (int h = 0; h < FH; h++) {
      if ((done >> h) & 1u) continue;
      int v = vox[h];
      if (v < 0) continue;
      float wsum = dep[h] * f[h];
      #pragma unroll
      for (int h2 = h + 1; h2 < FH; h2++) {
        if (vox[h2] == v) {
          wsum += dep[h2] * f[h2];
          done |= 1u << h2;
        }
      }
      atomicAdd(sb + (size_t)v*CAMC, wsum);
    }
  }
  __threadfence();
  grid.sync();

  // ---------------- Phase 4: gated transpose to out ----------------
  for (int t = gq; t < TPB; t += BPB) {
    const int v0 = t * 64;
    const int tx = tid & 63;
    const int ty = tid >> 6;            // 0..3
    float* dstp = out + (size_t)b*OUT_PER_B + v0;
    const bool isDirty = (aggDirty[b*MWPB + (t >> 5)] >> (t & 31)) & 1u;
    if (!isDirty) {
      #pragma unroll
      for (int r = ty; r < 64; r += 4)
        dstp[(size_t)r*KVOX + tx] = 0.0f;
      continue;
    }
    const float* s = scratch + ((size_t)b*KVOX + v0) * CAMC;
    __syncthreads();
    #pragma unroll
    for (int r = ty; r < 64; r += 4)
      u.tile[r][tx] = s[r*CAMC + tx];
    __syncthreads();
    #pragma unroll
    for (int r = ty; r < 64; r += 4)
      dstp[(size_t)r*KVOX + tx] = u.tile[tx][r];
  }
}

// ================= non-cooperative fallback (round-15 path) =================

__global__ __launch_bounds__(512) void lss_geom(const float* __restrict__ cam_out,
                                                const float* __restrict__ rots,
                                                const float* __restrict__ trans,
                                                const float* __restrict__ intrins,
                                                const float* __restrict__ post_rots,
                                                const float* __restrict__ post_trans,
                                                float* __restrict__ featT,
                                                int2* __restrict__ recs,
                                                unsigned* __restrict__ colMask) {
  #pragma clang fp contract(off)
  const int blk  = blockIdx.x;
  const int b    = blk & 7;
  const int j    = blk >> 3;
  const int bn   = b*NCAM + (j / FW);
  const int w    = j - (j / FW)*FW;
  const int col  = b*NCPB + j;
  const int tid  = threadIdx.x;
  const int wv   = tid >> 6;
  const int lane = tid & 63;

  __shared__ float sP[9], sM[9], sPT[3], sTR[3];
  __shared__ float sDep[FH][DNUM + 1];
  __shared__ int   sVox[FH][DNUM + 1];
  __shared__ unsigned sMask[MWPB];

  if (tid == 0) {
    float P[9], IC[9], M[9];
    inv3x3(post_rots + bn*9, P);
    inv3x3(intrins + bn*9, IC);
    const float* R = rots + bn*9;
    #pragma unroll
    for (int r = 0; r < 3; r++)
      #pragma unroll
      for (int k = 0; k < 3; k++)
        M[r*3+k] = (R[r*3+0]*IC[0+k] + R[r*3+1]*IC[3+k]) + R[r*3+2]*IC[6+k];
    #pragma unroll
    for (int q = 0; q < 9; q++) { sP[q] = P[q]; sM[q] = M[q]; }
  } else if (tid >= 8 && tid < 11) {
    sPT[tid-8]  = post_trans[bn*3 + (tid-8)];
  } else if (tid >= 11 && tid < 14) {
    sTR[tid-11] = trans[bn*3 + (tid-11)];
  } else if (tid >= 64 && tid < 64 + MWPB) {
    sMask[tid-64] = 0u;
  }

  const int colbase = bn*CAM_STRIDE + w;
  {
    int fh = tid >> 6, c = tid & 63;
    featT[((size_t)(col*FH + fh))*CAMC + c] = cam_out[colbase + (DNUM + c)*HW + fh*FW];
  }
  __syncthreads();

  const float fx = (float)((double)w * (351.0 / 21.0));
  {
    const int h = wv;
    float logit = (lane < DNUM) ? cam_out[colbase + lane*HW + h*FW] : -INFINITY;
    float mx = logit;
    #pragma unroll
    for (int off = 32; off >= 1; off >>= 1) mx = fmaxf(mx, __shfl_xor(mx, off, 64));
    float e = expf(logit - mx);
    float s = e;
    #pragma unroll
    for (int off = 32; off >= 1; off >>= 1) s += __shfl_xor(s, off, 64);
    if (lane < DNUM) {
      float fy = (float)((double)h * (127.0 / 7.0));
      float fz = 4.0f + (float)lane;
      float p0 = fx - sPT[0], p1 = fy - sPT[1], p2 = fz - sPT[2];
      float q0 = (sP[0]*p0 + sP[1]*p1) + sP[2]*p2;
      float q1 = (sP[3]*p0 + sP[4]*p1) + sP[5]*p2;
      float q2 = (sP[6]*p0 + sP[7]*p1) + sP[8]*p2;
      float r0 = q0*q2, r1 = q1*q2, r2 = q2;
      float g0 = ((sM[0]*r0 + sM[1]*r1) + sM[2]*r2) + sTR[0];
      float g1 = ((sM[3]*r0 + sM[4]*r1) + sM[5]*r2) + sTR[1];
      float g2 = ((sM[6]*r0 + sM[7]*r1) + sM[8]*r2) + sTR[2];
      int ix = (int)((g0 + 50.0f) / 0.5f);
      int iy = (int)((g1 + 50.0f) / 0.5f);
      int iz = (int)((g2 + 10.0f) / 20.0f);
      bool kept = (ix >= 0) & (ix < NXX) & (iy >= 0) & (iy < NXY) & (iz == 0);
      int v = ix*NXY + iy;
      sVox[h][lane] = kept ? v : -1;
      sDep[h][lane] = e / s;
      if (kept) {
        int t = v >> 6;
        atomicOr(&sMask[t >> 5], 1u << (t & 31));
      }
    }
  }
  __syncthreads();

  int2* __restrict__ rc = recs + (size_t)col*DNUM*FH;
  for (int e = tid; e < DNUM*FH; e += 512) {
    int d = e >> 3, h = e & 7;
    rc[e] = make_int2(sVox[h][d], __float_as_int(sDep[h][d]));
  }
  if (tid < MWPB) colMask[col*MWPB + tid] = sMask[tid];
}

__global__ __launch_bounds__(256) void lss_zero_dirty(const unsigned* __restrict__ colMask,
                                                      unsigned* __restrict__ aggDirty,
                                                      float4* __restrict__ ws4) {
  const int id  = blockIdx.x;
  const int b   = id & 7;
  const int t   = id >> 3;
  const int wd  = t >> 5, bit = t & 31;
  const int tid = threadIdx.x;

  __shared__ unsigned red[256];
  unsigned m = 0u;
  if (tid < NCPB) m = colMask[(size_t)(b*NCPB + tid)*MWPB + wd];
  red[tid] = m;
  __syncthreads();
  #pragma unroll
  for (int off = 128; off >= 1; off >>= 1) {
    if (tid < off) red[tid] |= red[tid + off];
    __syncthreads();
  }
  const unsigned word = red[0];
  if (tid == 0 && bit == 0) aggDirty[b*MWPB + wd] = word;
  if (!((word >> bit) & 1u)) return;

  const float4 z = make_float4(0.f, 0.f, 0.f, 0.f);
  float4* p = ws4 + (size_t)b*(OUT_PER_B/4) + (size_t)t*1024 + tid;
  p[0] = z; p[256] = z; p[512] = z; p[768] = z;
}

__global__ __launch_bounds__(256) void lss_atomic(const int2* __restrict__ recs,
                                                  const float* __restrict__ featT,
                                                  float* __restrict__ dst) {
  const int blk  = blockIdx.x;
  const int b    = blk & 7;
  const int q    = blk >> 3;
  const int wv   = (threadIdx.x >> 6);
  const int lane = threadIdx.x & 63;
  const int task = q*4 + wv;
  const int j    = task / DNUM;
  const int d    = task - j*DNUM;
  const int col  = b*NCPB + j;

  const int2* __restrict__ r8 = recs + ((size_t)col*DNUM + d)*FH;
  int   vox[FH];
  float dep[FH];
  #pragma unroll
  for (int h = 0; h < FH; h++) {
    int2 e = r8[h];
    vox[h] = e.x;
    dep[h] = __int_as_float(e.y);
  }
  float f[FH];
  const float* __restrict__ ft = featT + (size_t)col*FH*CAMC + lane;
  #pragma unroll
  for (int h = 0; h < FH; h++) f[h] = ft[h*CAMC];

  float* __restrict__ sb = dst + (size_t)b*OUT_PER_B + lane;
  unsigned done = 0;
  #pragma unroll
  for (int h = 0; h < FH; h++) {
    if ((done >> h) & 1u) continue;
    int v = vox[h];
    if (v < 0) continue;
    float wsum = dep[h] * f[h];
    #pragma unroll
    for (int h2 = h + 1; h2 < FH; h2++) {
      if (vox[h2] == v) {
        wsum += dep[h2] * f[h2];
        done |= 1u << h2;
      }
    }
    atomicAdd(sb + (size_t)v*CAMC, wsum);
  }
}

__global__ __launch_bounds__(256) void lss_transpose(const float* __restrict__ src,
                                                     const unsigned* __restrict__ aggDirty,
                                                     float* __restrict__ out) {
  __shared__ float tile[64][65];
  const int id = blockIdx.x;
  const int b  = id & 7;
  const int t  = id >> 3;
  const int v0 = t * 64;
  const int tx = threadIdx.x & 63;
  const int ty = threadIdx.x >> 6;
  float* dstp = out + (size_t)b*OUT_PER_B + v0;

  const bool isDirty = (aggDirty[b*MWPB + (t >> 5)] >> (t & 31)) & 1u;
  if (!isDirty) {
    #pragma unroll
    for (int r = ty; r < 64; r += 4)
      dstp[(size_t)r*KVOX + tx] = 0.0f;
    return;
  }
  const float* s = src + ((size_t)b*KVOX + v0) * CAMC;
  #pragma unroll
  for (int r = ty; r < 64; r += 4)
    tile[r][tx] = s[r*CAMC + tx];
  __syncthreads();
  #pragma unroll
  for (int r = ty; r < 64; r += 4)
    dstp[(size_t)r*KVOX + tx] = tile[tx][r];
}

// ---------------- fallback (tiny ws): round-1 direct atomic path ----------------
__global__ void lss_prep(const float* __restrict__ rots,
                         const float* __restrict__ intrins,
                         const float* __restrict__ post_rots,
                         float* __restrict__ prep) {
  #pragma clang fp contract(off)
  int bn = threadIdx.x;
  if (bn >= BN) return;
  float P[9], IC[9];
  inv3x3(post_rots + bn*9, P);
  inv3x3(intrins + bn*9, IC);
  const float* R = rots + bn*9;
  float* o = prep + bn*18;
  #pragma unroll
  for (int q = 0; q < 9; q++) o[q] = P[q];
  #pragma unroll
  for (int r = 0; r < 3; r++)
    #pragma unroll
    for (int k = 0; k < 3; k++)
      o[9 + r*3 + k] = (R[r*3+0]*IC[0+k] + R[r*3+1]*IC[3+k]) + R[r*3+2]*IC[6+k];
}

__global__ __launch_bounds__(64) void lss_scatter_direct(const float* __restrict__ cam_out,
                                                         const float* __restrict__ trans,
                                                         const float* __restrict__ post_trans,
                                                         const float* __restrict__ prep,
                                                         float* __restrict__ out) {
  #pragma clang fp contract(off)
  const int blk = blockIdx.x;
  const int bn  = blk / HW;
  const int pix = blk % HW;
  const int h   = pix / FW;
  const int w   = pix % FW;
  const int b   = bn / NCAM;
  const int tid = threadIdx.x;
  __shared__ float sP[9], sM[9], sPT[3], sTR[3];
  __shared__ float sDepth[DNUM];
  __shared__ int   sVoff[DNUM];
  if (tid < 9)       sP[tid]      = prep[bn*18 + tid];
  else if (tid < 18) sM[tid-9]    = prep[bn*18 + tid];
  else if (tid < 21) sPT[tid-18]  = post_trans[bn*3 + (tid-18)];
  else if (tid < 24) sTR[tid-21]  = trans[bn*3 + (tid-21)];
  __syncthreads();
  const int base = bn*CAM_STRIDE + h*FW + w;
  float logit = (tid < DNUM) ? cam_out[base + tid*HW] : -INFINITY;
  float mx = logit;
  #pragma unroll
  for (int off = 32; off >= 1; off >>= 1) mx = fmaxf(mx, __shfl_xor(mx, off, 64));
  float e = expf(logit - mx);
  float s = e;
  #pragma unroll
  for (int off = 32; off >= 1; off >>= 1) s += __shfl_xor(s, off, 64);
  float depth = e / s;
  if (tid < DNUM) {
    float fx = (float)((double)w * (351.0 / 21.0));
    float fy = (float)((double)h * (127.0 / 7.0));
    float fz = 4.0f + (float)tid;
    float p0 = fx - sPT[0], p1 = fy - sPT[1], p2 = fz - sPT[2];
    float q0 = (sP[0]*p0 + sP[1]*p1) + sP[2]*p2;
    float q1 = (sP[3]*p0 + sP[4]*p1) + sP[5]*p2;
    float q2 = (sP[6]*p0 + sP[7]*p1) + sP[8]*p2;
    float r0 = q0*q2, r1 = q1*q2, r2 = q2;
    float g0 = ((sM[0]*r0 + sM[1]*r1) + sM[2]*r2) + sTR[0];
    float g1 = ((sM[3]*r0 + sM[4]*r1) + sM[5]*r2) + sTR[1];
    float g2 = ((sM[6]*r0 + sM[7]*r1) + sM[8]*r2) + sTR[2];
    int ix = (int)((g0 + 50.0f) / 0.5f);
    int iy = (int)((g1 + 50.0f) / 0.5f);
    int iz = (int)((g2 + 10.0f) / 20.0f);
    bool kept = (ix >= 0) & (ix < NXX) & (iy >= 0) & (iy < NXY) & (iz == 0);
    sVoff[tid]  = kept ? (ix*NXY + iy) : -1;
    sDepth[tid] = depth;
  }
  __syncthreads();
  const float feat = cam_out[base + (DNUM + tid)*HW];
  float* outb = out + (size_t)b*OUT_PER_B + (size_t)tid*KVOX;
  #pragma unroll 1
  for (int d = 0; d < DNUM; d++) {
    int v = sVoff[d];
    if (v >= 0) atomicAdd(outb + v, sDepth[d] * feat);
  }
}

extern "C" void kernel_launch(void* const* d_in, const int* in_sizes, int n_in,
                              void* d_out, int out_size, void* d_ws, size_t ws_size,
                              hipStream_t stream) {
  const float* cam_out    = (const float*)d_in[0];
  const float* rots       = (const float*)d_in[1];
  const float* trans      = (const float*)d_in[2];
  const float* intrins    = (const float*)d_in[3];
  const float* post_rots  = (const float*)d_in[4];
  const float* post_trans = (const float*)d_in[5];
  float* out = (float*)d_out;
  char*  ws  = (char*)d_ws;

  // ws layout: scratch (82 MB) | featT (2.2 MB) | recs (2.8 MB) |
  //            colMask (84 KB) | aggDirty (640 B)
  float*    scratch  = (float*)ws;
  float*    featT    = scratch + SCRATCH_FLOATS;
  int2*     recs     = (int2*)(featT + (size_t)PIXT*CAMC);
  unsigned* colMask  = (unsigned*)(recs + NPTS);
  unsigned* aggDirty = colMask + (size_t)NCOL*MWPB;
  const size_t need = SCRATCH_FLOATS*4 + (size_t)PIXT*CAMC*4 + (size_t)NPTS*8
                      + ((size_t)NCOL*MWPB + NB*MWPB)*4;

  if (ws_size >= need) {
    int dev = 0, coop = 0, numCU = 0, maxB = 0;
    hipGetDevice(&dev);
    hipDeviceGetAttribute(&coop, hipDeviceAttributeCooperativeLaunch, dev);
    hipDeviceGetAttribute(&numCU, hipDeviceAttributeMultiprocessorCount, dev);
    if (coop) hipOccupancyMaxActiveBlocksPerMultiprocessor(&maxB, lss_fused, 256, 0);

    if (coop && maxB > 0 && numCU > 0) {
      int ng = maxB * numCU;
      if (ng > 2048) ng = 2048;
      ng &= ~7;                      // multiple of 8 for XCD pinning
      if (ng < 8) ng = 8;
      void* args[] = { (void*)&cam_out, (void*)&rots, (void*)&trans,
                       (void*)&intrins, (void*)&post_rots, (void*)&post_trans,
                       (void*)&featT, (void*)&recs, (void*)&colMask,
                       (void*)&aggDirty, (void*)&scratch, (void*)&out };
      hipLaunchCooperativeKernel((const void*)lss_fused, dim3(ng), dim3(256),
                                 args, 0, stream);
    } else {
      lss_geom<<<NCOL, 512, 0, stream>>>(cam_out, rots, trans, intrins,
                                         post_rots, post_trans, featT, recs, colMask);
      lss_zero_dirty<<<NB * TPB, 256, 0, stream>>>(colMask, aggDirty, (float4*)scratch);
      lss_atomic<<<QUADS_PB * 8, 256, 0, stream>>>(recs, featT, scratch);
      lss_transpose<<<NB * TPB, 256, 0, stream>>>(scratch, aggDirty, out);
    }
  } else {
    float* prep = (float*)ws;
    hipMemsetAsync(out, 0, (size_t)out_size * sizeof(float), stream);
    lss_prep<<<1, 64, 0, stream>>>(rots, intrins, post_rots, prep);
    lss_scatter_direct<<<BN * HW, 64, 0, stream>>>(cam_out, trans, post_trans, prep, out);
  }
}

// Round 17
// 73.521 us; speedup vs baseline: 4.8329x; 4.8329x over previous
//
#include <hip/hip_runtime.h>
#include <math.h>

// LiftSplatShoot constants
#define DNUM 41
#define FH 8
#define FW 22
#define CAMC 64
#define NB 8
#define NCAM 6
#define BN 48
#define NXX 200
#define NXY 200
#define KVOX 40000                // NXX*NXY (NXZ=1)
#define CAM_CH (DNUM + CAMC)      // 105
#define HW (FH * FW)              // 176
#define CAM_STRIDE (CAM_CH * HW)  // 18480
#define OUT_PER_B (CAMC * KVOX)   // 2,560,000 floats per batch (scratch & out)
#define SCRATCH_FLOATS ((size_t)NB * KVOX * CAMC)   // 20,480,000 floats = 81.92 MB
#define NCPB (NCAM * FW)          // 132 columns per batch
#define NCOL (NB * NCPB)          // 1056 columns total
#define PIXT (NCOL * FH)          // 8448 pixels
#define NPTS (NCOL * FH * DNUM)   // 346,368 points
#define TASKS_PB (NCPB * DNUM)    // 5412 (col,depth) tasks per batch
#define ATOM_BLKS_PB (TASKS_PB / 4)  // 1353 blocks per batch (4 waves each)
#define TPB 625                   // tiles (64 voxels) per batch
#define MWPB 20                   // bitmap words per batch (20*32 >= 625)

// Replicates reference safe_inverse_3x3 in float32, same op order, no fma.
__device__ __forceinline__ void inv3x3(const float* __restrict__ m, float* __restrict__ o) {
  #pragma clang fp contract(off)
  float a=m[0], b=m[1], c=m[2];
  float d=m[3], e=m[4], f=m[5];
  float g=m[6], h=m[7], i=m[8];
  float A  =  e*i - f*h;
  float Bc = -(d*i - f*g);
  float Cc =  d*h - e*g;
  float Dc = -(b*i - c*h);
  float E  =  a*i - c*g;
  float F  = -(a*h - b*g);
  float G  =  b*f - c*e;
  float H  = -(a*f - c*d);
  float I  =  a*e - b*d;
  float det = fmaxf((a*A + b*Bc) + c*Cc, 1e-8f);
  o[0]=A/det;  o[1]=Dc/det; o[2]=G/det;
  o[3]=Bc/det; o[4]=E/det;  o[5]=H/det;
  o[6]=Cc/det; o[7]=F/det;  o[8]=I/det;
}

// Phase 1: one 512-thread block per column, XCD-pinned (blk = j*8 + b).
// Softmax + geometry -> records (vox,dep), featT, per-column tile mask
// (plain stores — no clearing/atomics needed, overwritten every call).
__global__ __launch_bounds__(512) void lss_geom(const float* __restrict__ cam_out,
                                                const float* __restrict__ rots,
                                                const float* __restrict__ trans,
                                                const float* __restrict__ intrins,
                                                const float* __restrict__ post_rots,
                                                const float* __restrict__ post_trans,
                                                float* __restrict__ featT,
                                                int2* __restrict__ recs,
                                                unsigned* __restrict__ colMask) {
  #pragma clang fp contract(off)
  const int blk  = blockIdx.x;        // 0 .. NCOL-1
  const int b    = blk & 7;           // XCD-pinned batch
  const int j    = blk >> 3;          // 0..131 column within batch
  const int bn   = b*NCAM + (j / FW);
  const int w    = j - (j / FW)*FW;
  const int col  = b*NCPB + j;        // global column index for featT/recs
  const int tid  = threadIdx.x;
  const int wv   = tid >> 6;          // wave id 0..7 == row h
  const int lane = tid & 63;

  __shared__ float sP[9], sM[9], sPT[3], sTR[3];
  __shared__ float sDep[FH][DNUM + 1];
  __shared__ int   sVox[FH][DNUM + 1];
  __shared__ unsigned sMask[MWPB];

  if (tid == 0) {
    float P[9], IC[9], M[9];
    inv3x3(post_rots + bn*9, P);
    inv3x3(intrins + bn*9, IC);
    const float* R = rots + bn*9;
    #pragma unroll
    for (int r = 0; r < 3; r++)
      #pragma unroll
      for (int k = 0; k < 3; k++)
        M[r*3+k] = (R[r*3+0]*IC[0+k] + R[r*3+1]*IC[3+k]) + R[r*3+2]*IC[6+k];
    #pragma unroll
    for (int q = 0; q < 9; q++) { sP[q] = P[q]; sM[q] = M[q]; }
  } else if (tid >= 8 && tid < 11) {
    sPT[tid-8]  = post_trans[bn*3 + (tid-8)];
  } else if (tid >= 11 && tid < 14) {
    sTR[tid-11] = trans[bn*3 + (tid-11)];
  } else if (tid >= 64 && tid < 64 + MWPB) {
    sMask[tid-64] = 0u;
  }

  const int colbase = bn*CAM_STRIDE + w;   // + c*HW + h*FW

  // featT: global->reg->global, write side fully coalesced (256B runs)
  {
    int fh = tid >> 6, c = tid & 63;
    float fv = cam_out[colbase + (DNUM + c)*HW + fh*FW];
    featT[((size_t)(col*FH + fh))*CAMC + c] = fv;
  }
  __syncthreads();

  const float fx = (float)((double)w * (351.0 / 21.0));

  // per-row softmax + geometry: wave wv handles row h = wv (lane = depth)
  {
    const int h = wv;
    float logit = (lane < DNUM) ? cam_out[colbase + lane*HW + h*FW] : -INFINITY;
    float mx = logit;
    #pragma unroll
    for (int off = 32; off >= 1; off >>= 1) mx = fmaxf(mx, __shfl_xor(mx, off, 64));
    float e = expf(logit - mx);
    float s = e;
    #pragma unroll
    for (int off = 32; off >= 1; off >>= 1) s += __shfl_xor(s, off, 64);
    if (lane < DNUM) {
      float fy = (float)((double)h * (127.0 / 7.0));
      float fz = 4.0f + (float)lane;
      float p0 = fx - sPT[0], p1 = fy - sPT[1], p2 = fz - sPT[2];
      float q0 = (sP[0]*p0 + sP[1]*p1) + sP[2]*p2;
      float q1 = (sP[3]*p0 + sP[4]*p1) + sP[5]*p2;
      float q2 = (sP[6]*p0 + sP[7]*p1) + sP[8]*p2;
      float r0 = q0*q2, r1 = q1*q2, r2 = q2;
      float g0 = ((sM[0]*r0 + sM[1]*r1) + sM[2]*r2) + sTR[0];
      float g1 = ((sM[3]*r0 + sM[4]*r1) + sM[5]*r2) + sTR[1];
      float g2 = ((sM[6]*r0 + sM[7]*r1) + sM[8]*r2) + sTR[2];
      int ix = (int)((g0 + 50.0f) / 0.5f);
      int iy = (int)((g1 + 50.0f) / 0.5f);
      int iz = (int)((g2 + 10.0f) / 20.0f);
      bool kept = (ix >= 0) & (ix < NXX) & (iy >= 0) & (iy < NXY) & (iz == 0);
      int v = ix*NXY + iy;
      sVox[h][lane] = kept ? v : -1;
      sDep[h][lane] = e / s;
      if (kept) {
        int t = v >> 6;
        atomicOr(&sMask[t >> 5], 1u << (t & 31));   // LDS dedup
      }
    }
  }
  __syncthreads();

  // records: rec[(col*41 + d)*8 + h], coalesced 8B writes (e = d*8+h)
  int2* __restrict__ rc = recs + (size_t)col*DNUM*FH;
  for (int e = tid; e < DNUM*FH; e += 512) {
    int d = e >> 3, h = e & 7;
    rc[e] = make_int2(sVox[h][d], __float_as_int(sDep[h][d]));
  }
  // publish per-column mask (plain store, no clear needed)
  if (tid < MWPB) colMask[col*MWPB + tid] = sMask[tid];
}

// Zero ONLY dirty tiles of scratch; also publishes the aggregated dirty
// bitmap for the transpose. Grid 8*625, XCD-pinned (id&7 = b).
__global__ __launch_bounds__(256) void lss_zero_dirty(const unsigned* __restrict__ colMask,
                                                      unsigned* __restrict__ aggDirty,
                                                      float4* __restrict__ ws4) {
  const int id  = blockIdx.x;
  const int b   = id & 7;
  const int t   = id >> 3;                         // tile 0..624
  const int wd  = t >> 5, bit = t & 31;
  const int tid = threadIdx.x;

  __shared__ unsigned red[256];
  unsigned m = 0u;
  if (tid < NCPB) m = colMask[(size_t)(b*NCPB + tid)*MWPB + wd];
  red[tid] = m;
  __syncthreads();
  #pragma unroll
  for (int off = 128; off >= 1; off >>= 1) {
    if (tid < off) red[tid] |= red[tid + off];
    __syncthreads();
  }
  const unsigned word = red[0];
  if (tid == 0 && bit == 0) aggDirty[b*MWPB + wd] = word;  // one writer per (b,wd)
  if (!((word >> bit) & 1u)) return;

  // zero tile: 64 vox * 64 ch = 1024 float4; 256 threads x 4
  const float4 z = make_float4(0.f, 0.f, 0.f, 0.f);
  float4* p = ws4 + (size_t)b*(OUT_PER_B/4) + (size_t)t*1024 + tid;
  p[0] = z; p[256] = z; p[512] = z; p[768] = z;
}

// Phase 2: pure atomic kernel. One wave per (col,d) task; 4 waves/block;
// grid = 1353*8, XCD-pinned (blk&7 = b). Register-only h-merge, then
// coalesced merged atomics (64 lanes -> 4 cache lines, XCD-local).
__global__ __launch_bounds__(256) void lss_atomic(const int2* __restrict__ recs,
                                                  const float* __restrict__ featT,
                                                  float* __restrict__ dst) {
  const int blk  = blockIdx.x;
  const int b    = blk & 7;
  const int q    = blk >> 3;          // 0..1352
  const int wv   = (threadIdx.x >> 6);
  const int lane = threadIdx.x & 63;
  const int task = q*4 + wv;          // 0..5411
  const int j    = task / DNUM;
  const int d    = task - j*DNUM;
  const int col  = b*NCPB + j;

  const int2* __restrict__ r8 = recs + ((size_t)col*DNUM + d)*FH;
  int   vox[FH];
  float dep[FH];
  #pragma unroll
  for (int h = 0; h < FH; h++) {
    int2 e = r8[h];
    vox[h] = e.x;
    dep[h] = __int_as_float(e.y);
  }

  float f[FH];
  const float* __restrict__ ft = featT + (size_t)col*FH*CAMC + lane;
  #pragma unroll
  for (int h = 0; h < FH; h++) f[h] = ft[h*CAMC];

  float* __restrict__ sb = dst + (size_t)b*OUT_PER_B + lane;
  unsigned done = 0;
  #pragma unroll
  for (int h = 0; h < FH; h++) {
    if ((done >> h) & 1u) continue;
    int v = vox[h];                   // register, wave-uniform
    if (v < 0) continue;
    float wsum = dep[h] * f[h];
    #pragma unroll
    for (int h2 = h + 1; h2 < FH; h2++) {
      if (vox[h2] == v) {
        wsum += dep[h2] * f[h2];
        done |= 1u << h2;
      }
    }
    atomicAdd(sb + (size_t)v*CAMC, wsum);
  }
}

// (B, XY, C) -> (B, C, XY) tiled transpose, XCD-pinned by batch.
// Clean tiles (dirty bit unset) write zeros directly — no scratch read.
__global__ __launch_bounds__(256) void lss_transpose(const float* __restrict__ src,
                                                     const unsigned* __restrict__ aggDirty,
                                                     float* __restrict__ out) {
  __shared__ float tile[64][65];
  const int id = blockIdx.x;
  const int b  = id & 7;
  const int t  = id >> 3;                         // tile 0..624
  const int v0 = t * 64;
  const int tx = threadIdx.x & 63;
  const int ty = threadIdx.x >> 6;                // 0..3
  float* dstp = out + (size_t)b*OUT_PER_B + v0;

  const bool isDirty = (aggDirty[b*MWPB + (t >> 5)] >> (t & 31)) & 1u;
  if (!isDirty) {
    #pragma unroll
    for (int r = ty; r < 64; r += 4)
      dstp[(size_t)r*KVOX + tx] = 0.0f;           // coalesced zero-fill
    return;
  }

  const float* s = src + ((size_t)b*KVOX + v0) * CAMC;
  #pragma unroll
  for (int r = ty; r < 64; r += 4)
    tile[r][tx] = s[r*CAMC + tx];                 // coalesced
  __syncthreads();
  #pragma unroll
  for (int r = ty; r < 64; r += 4)
    dstp[(size_t)r*KVOX + tx] = tile[tx][r];      // coalesced, bank-conflict-free
}

// ---------------- fallback (tiny ws): round-1 direct atomic path ----------------
__global__ void lss_prep(const float* __restrict__ rots,
                         const float* __restrict__ intrins,
                         const float* __restrict__ post_rots,
                         float* __restrict__ prep) {
  #pragma clang fp contract(off)
  int bn = threadIdx.x;
  if (bn >= BN) return;
  float P[9], IC[9];
  inv3x3(post_rots + bn*9, P);
  inv3x3(intrins + bn*9, IC);
  const float* R = rots + bn*9;
  float* o = prep + bn*18;
  #pragma unroll
  for (int q = 0; q < 9; q++) o[q] = P[q];
  #pragma unroll
  for (int r = 0; r < 3; r++)
    #pragma unroll
    for (int k = 0; k < 3; k++)
      o[9 + r*3 + k] = (R[r*3+0]*IC[0+k] + R[r*3+1]*IC[3+k]) + R[r*3+2]*IC[6+k];
}

__global__ __launch_bounds__(64) void lss_scatter_direct(const float* __restrict__ cam_out,
                                                         const float* __restrict__ trans,
                                                         const float* __restrict__ post_trans,
                                                         const float* __restrict__ prep,
                                                         float* __restrict__ out) {
  #pragma clang fp contract(off)
  const int blk = blockIdx.x;
  const int bn  = blk / HW;
  const int pix = blk % HW;
  const int h   = pix / FW;
  const int w   = pix % FW;
  const int b   = bn / NCAM;
  const int tid = threadIdx.x;
  __shared__ float sP[9], sM[9], sPT[3], sTR[3];
  __shared__ float sDepth[DNUM];
  __shared__ int   sVoff[DNUM];
  if (tid < 9)       sP[tid]      = prep[bn*18 + tid];
  else if (tid < 18) sM[tid-9]    = prep[bn*18 + tid];
  else if (tid < 21) sPT[tid-18]  = post_trans[bn*3 + (tid-18)];
  else if (tid < 24) sTR[tid-21]  = trans[bn*3 + (tid-21)];
  __syncthreads();
  const int base = bn*CAM_STRIDE + h*FW + w;
  float logit = (tid < DNUM) ? cam_out[base + tid*HW] : -INFINITY;
  float mx = logit;
  #pragma unroll
  for (int off = 32; off >= 1; off >>= 1) mx = fmaxf(mx, __shfl_xor(mx, off, 64));
  float e = expf(logit - mx);
  float s = e;
  #pragma unroll
  for (int off = 32; off >= 1; off >>= 1) s += __shfl_xor(s, off, 64);
  float depth = e / s;
  if (tid < DNUM) {
    float fx = (float)((double)w * (351.0 / 21.0));
    float fy = (float)((double)h * (127.0 / 7.0));
    float fz = 4.0f + (float)tid;
    float p0 = fx - sPT[0], p1 = fy - sPT[1], p2 = fz - sPT[2];
    float q0 = (sP[0]*p0 + sP[1]*p1) + sP[2]*p2;
    float q1 = (sP[3]*p0 + sP[4]*p1) + sP[5]*p2;
    float q2 = (sP[6]*p0 + sP[7]*p1) + sP[8]*p2;
    float r0 = q0*q2, r1 = q1*q2, r2 = q2;
    float g0 = ((sM[0]*r0 + sM[1]*r1) + sM[2]*r2) + sTR[0];
    float g1 = ((sM[3]*r0 + sM[4]*r1) + sM[5]*r2) + sTR[1];
    float g2 = ((sM[6]*r0 + sM[7]*r1) + sM[8]*r2) + sTR[2];
    int ix = (int)((g0 + 50.0f) / 0.5f);
    int iy = (int)((g1 + 50.0f) / 0.5f);
    int iz = (int)((g2 + 10.0f) / 20.0f);
    bool kept = (ix >= 0) & (ix < NXX) & (iy >= 0) & (iy < NXY) & (iz == 0);
    sVoff[tid]  = kept ? (ix*NXY + iy) : -1;
    sDepth[tid] = depth;
  }
  __syncthreads();
  const float feat = cam_out[base + (DNUM + tid)*HW];
  float* outb = out + (size_t)b*OUT_PER_B + (size_t)tid*KVOX;
  #pragma unroll 1
  for (int d = 0; d < DNUM; d++) {
    int v = sVoff[d];
    if (v >= 0) atomicAdd(outb + v, sDepth[d] * feat);
  }
}

extern "C" void kernel_launch(void* const* d_in, const int* in_sizes, int n_in,
                              void* d_out, int out_size, void* d_ws, size_t ws_size,
                              hipStream_t stream) {
  const float* cam_out    = (const float*)d_in[0];
  const float* rots       = (const float*)d_in[1];
  const float* trans      = (const float*)d_in[2];
  const float* intrins    = (const float*)d_in[3];
  const float* post_rots  = (const float*)d_in[4];
  const float* post_trans = (const float*)d_in[5];
  float* out = (float*)d_out;
  char*  ws  = (char*)d_ws;

  // ws layout: scratch (82 MB) | featT (2.2 MB) | recs (2.8 MB) |
  //            colMask (84 KB) | aggDirty (640 B)
  float*    scratch  = (float*)ws;
  float*    featT    = scratch + SCRATCH_FLOATS;             // PIXT*CAMC floats
  int2*     recs     = (int2*)(featT + (size_t)PIXT*CAMC);   // NPTS int2 (8B-aligned)
  unsigned* colMask  = (unsigned*)(recs + NPTS);             // NCOL*MWPB
  unsigned* aggDirty = colMask + (size_t)NCOL*MWPB;          // NB*MWPB
  const size_t need = SCRATCH_FLOATS*4 + (size_t)PIXT*CAMC*4 + (size_t)NPTS*8
                      + ((size_t)NCOL*MWPB + NB*MWPB)*4;

  if (ws_size >= need) {
    lss_geom<<<NCOL, 512, 0, stream>>>(cam_out, rots, trans, intrins,
                                       post_rots, post_trans, featT, recs, colMask);
    lss_zero_dirty<<<NB * TPB, 256, 0, stream>>>(colMask, aggDirty, (float4*)scratch);
    lss_atomic<<<ATOM_BLKS_PB * 8, 256, 0, stream>>>(recs, featT, scratch);
    lss_transpose<<<NB * TPB, 256, 0, stream>>>(scratch, aggDirty, out);
  } else {
    float* prep = (float*)ws;   // BN*18 floats
    hipMemsetAsync(out, 0, (size_t)out_size * sizeof(float), stream);
    lss_prep<<<1, 64, 0, stream>>>(rots, intrins, post_rots, prep);
    lss_scatter_direct<<<BN * HW, 64, 0, stream>>>(cam_out, trans, post_trans, prep, out);
  }
}